// Round 1
// baseline (338.895 us; speedup 1.0000x reference)
//
#include <hip/hip_runtime.h>
#include <stdint.h>

typedef float f32x4 __attribute__((ext_vector_type(4)));
typedef __bf16 bf16x8 __attribute__((ext_vector_type(8)));
typedef unsigned short u16x8 __attribute__((ext_vector_type(8)));

#define DEV __device__ __forceinline__

DEV unsigned short f2bf(float f) {
  unsigned int u = __float_as_uint(f);
  unsigned int r = (u + 0x7FFFu + ((u >> 16) & 1u)) >> 16;
  return (unsigned short)r;
}
DEV float b2f(unsigned short h) { return __uint_as_float(((unsigned int)h) << 16); }

DEV void gload16(const void* g, void* l) {
  __builtin_amdgcn_global_load_lds((__attribute__((address_space(1))) void*)(g),
                                   (__attribute__((address_space(3))) void*)(l), 16, 0, 0);
}

// ---------------- fp32 -> bf16 cast (vectorized) ----------------
__global__ void cast_bf16_kernel(const float* __restrict__ in,
                                 unsigned short* __restrict__ out, int n8) {
  int i = blockIdx.x * 256 + threadIdx.x;
  if (i >= n8) return;
  const float4* p = (const float4*)in + (size_t)i * 2;
  float4 a = p[0], b = p[1];
  u16x8 o;
  o[0] = f2bf(a.x); o[1] = f2bf(a.y); o[2] = f2bf(a.z); o[3] = f2bf(a.w);
  o[4] = f2bf(b.x); o[5] = f2bf(b.y); o[6] = f2bf(b.z); o[7] = f2bf(b.w);
  ((u16x8*)out)[i] = o;
}

// ---------------- bf16 GEMM, B^T layout (out[m,n] = sum_k A[m,k]*W[n,k]) ----
// MODE 0: plain fp32 store to out0 (row-major MxN)
// MODE 1: qkv scatter: N=3072 = [Q|K|V], elu+1 on Q,K; store bf16 [b][h][l][d]
template<int MODE>
__global__ __launch_bounds__(256, 2) void gemm_bt(
    const unsigned short* __restrict__ A, const unsigned short* __restrict__ Bw,
    void* __restrict__ out0, unsigned short* __restrict__ qp,
    unsigned short* __restrict__ kp, unsigned short* __restrict__ vp,
    int K, int N, int nTn)
{
  __shared__ unsigned short sA[128 * 64];
  __shared__ unsigned short sB[128 * 64];
  int t = threadIdx.x, w = t >> 6, lane = t & 63, fr = lane & 15, fq = lane >> 4;
  int bid = blockIdx.x;
  int bm = bid / nTn, bn = bid % nTn;
  int wm = w >> 1, wn = w & 1;

  f32x4 acc[4][4];
  f32x4 z4 = {0.f, 0.f, 0.f, 0.f};
#pragma unroll
  for (int mi = 0; mi < 4; ++mi)
#pragma unroll
    for (int ni = 0; ni < 4; ++ni) acc[mi][ni] = z4;

  for (int k0 = 0; k0 < K; k0 += 64) {
#pragma unroll
    for (int i = 0; i < 4; ++i) {
      int p = (i * 4 + w) * 64 + lane;
      int r = p >> 3;
      int c8 = (p & 7) ^ (r & 7);  // inverse-swizzled source column-chunk
      gload16(A + (size_t)(bm * 128 + r) * K + k0 + c8 * 8, &sA[(i * 4 + w) * 512]);
      gload16(Bw + (size_t)(bn * 128 + r) * K + k0 + c8 * 8, &sB[(i * 4 + w) * 512]);
    }
    __syncthreads();
#pragma unroll
    for (int ks = 0; ks < 2; ++ks) {
      bf16x8 af[4], bg[4];
#pragma unroll
      for (int mi = 0; mi < 4; ++mi) {
        int r = wm * 64 + mi * 16 + fr;
        int c8 = (ks * 4 + fq) ^ (r & 7);
        af[mi] = *(const bf16x8*)&sA[(r * 8 + c8) * 8];
      }
#pragma unroll
      for (int ni = 0; ni < 4; ++ni) {
        int r = wn * 64 + ni * 16 + fr;
        int c8 = (ks * 4 + fq) ^ (r & 7);
        bg[ni] = *(const bf16x8*)&sB[(r * 8 + c8) * 8];
      }
#pragma unroll
      for (int mi = 0; mi < 4; ++mi)
#pragma unroll
        for (int ni = 0; ni < 4; ++ni)
          acc[mi][ni] = __builtin_amdgcn_mfma_f32_16x16x32_bf16(af[mi], bg[ni], acc[mi][ni], 0, 0, 0);
    }
    __syncthreads();
  }

  if (MODE == 0) {
    float* O = (float*)out0;
#pragma unroll
    for (int mi = 0; mi < 4; ++mi)
#pragma unroll
      for (int ni = 0; ni < 4; ++ni)
#pragma unroll
        for (int j = 0; j < 4; ++j) {
          int m = bm * 128 + wm * 64 + mi * 16 + fq * 4 + j;
          int n = bn * 128 + wn * 64 + ni * 16 + fr;
          O[(size_t)m * N + n] = acc[mi][ni][j];
        }
  } else {
    int tsel = (bn * 128) >> 10;  // 0:Q 1:K 2:V (whole block in one tensor)
    unsigned short* base = (tsel == 0) ? qp : ((tsel == 1) ? kp : vp);
#pragma unroll
    for (int mi = 0; mi < 4; ++mi)
#pragma unroll
      for (int ni = 0; ni < 4; ++ni)
#pragma unroll
        for (int j = 0; j < 4; ++j) {
          int m = bm * 128 + wm * 64 + mi * 16 + fq * 4 + j;  // b*4096 + l
          int n = bn * 128 + wn * 64 + ni * 16 + fr;
          int col1 = n & 1023;
          int h = col1 >> 6, d = col1 & 63;
          int b = m >> 12, l = m & 4095;
          float v = acc[mi][ni][j];
          if (tsel < 2) v = (v > 0.f) ? (v + 1.f) : __expf(v);  // elu(v)+1
          base[(((size_t)(b * 16 + h)) * 4096 + l) * 64 + d] = f2bf(v);
        }
  }
}

// ---------------- pass 1: per-chunk state S_c = k^T v (64x64), z_c = sum k ---
__global__ __launch_bounds__(256) void chunk_state(
    const unsigned short* __restrict__ kb, const unsigned short* __restrict__ vb,
    float* __restrict__ Sbuf, float* __restrict__ zbuf)
{
  __shared__ unsigned short sk[128 * 64];
  __shared__ unsigned short sv[128 * 64];
  int t = threadIdx.x, w = t >> 6;
  int bh = blockIdx.x >> 5, c = blockIdx.x & 31;
  size_t base = ((size_t)bh * 4096 + (size_t)c * 128) * 64;
#pragma unroll
  for (int i = 0; i < 4; ++i) {
    int p = (i * 4 + w) * 64 + (t & 63);
    gload16(kb + base + (size_t)p * 8, &sk[(i * 4 + w) * 512]);
    gload16(vb + base + (size_t)p * 8, &sv[(i * 4 + w) * 512]);
  }
  __syncthreads();
  int d = t >> 2, e0 = (t & 3) << 4;
  float acc[16];
#pragma unroll
  for (int j = 0; j < 16; ++j) acc[j] = 0.f;
#pragma unroll 4
  for (int s = 0; s < 128; ++s) {
    float kv = b2f(sk[s * 64 + d]);
    u16x8 v0 = *(const u16x8*)&sv[s * 64 + e0];
    u16x8 v1 = *(const u16x8*)&sv[s * 64 + e0 + 8];
#pragma unroll
    for (int j = 0; j < 8; ++j) {
      acc[j] += kv * b2f(v0[j]);
      acc[8 + j] += kv * b2f(v1[j]);
    }
  }
  size_t ob = ((size_t)bh * 32 + c) * 4096 + d * 64 + e0;
#pragma unroll
  for (int j = 0; j < 16; j += 4) {
    f32x4 st = {acc[j], acc[j + 1], acc[j + 2], acc[j + 3]};
    *(f32x4*)&Sbuf[ob + j] = st;
  }
  if (t < 64) {
    float z = 0.f;
#pragma unroll 8
    for (int s = 0; s < 128; ++s) z += b2f(sk[s * 64 + t]);
    zbuf[((size_t)bh * 32 + c) * 64 + t] = z;
  }
}

// ---------------- pass 2: exclusive prefix over chunks; S -> bf16 transposed -
__global__ __launch_bounds__(256) void scan_state(
    const float* __restrict__ Sbuf, const float* __restrict__ zbuf,
    unsigned short* __restrict__ Spref, float* __restrict__ zpref)
{
  int t = threadIdx.x;
  int bh = blockIdx.x;
  f32x4 run[4];
  f32x4 z4 = {0.f, 0.f, 0.f, 0.f};
#pragma unroll
  for (int r = 0; r < 4; ++r) run[r] = z4;
  float zrun = 0.f;
  for (int c = 0; c < 32; ++c) {
    size_t base = ((size_t)bh * 32 + c) * 4096;
#pragma unroll
    for (int r = 0; r < 4; ++r) {
      int i0 = r * 1024 + t * 4;
      f32x4 old = *(const f32x4*)&Sbuf[base + i0];
      int dd = i0 >> 6, e = i0 & 63;
#pragma unroll
      for (int j = 0; j < 4; ++j)
        Spref[base + (size_t)(e + j) * 64 + dd] = f2bf(run[r][j]);  // [e][d]
      run[r] += old;
    }
    if (t < 64) {
      size_t zi = ((size_t)bh * 32 + c) * 64 + t;
      zpref[zi] = zrun;
      zrun += zbuf[zi];
    }
  }
}

// ---------------- pass 3: per-chunk output ----------------------------------
__global__ __launch_bounds__(256, 2) void chunk_out(
    const unsigned short* __restrict__ qb, const unsigned short* __restrict__ kb,
    const unsigned short* __restrict__ vb, const unsigned short* __restrict__ Spref,
    const float* __restrict__ zpref, unsigned short* __restrict__ attn)
{
  __shared__ unsigned short sq[128 * 64];   // q, swizzled (&7)
  __shared__ unsigned short skv[128 * 64];  // k (swz &7), then v^T [64][128] (swz &15)
  __shared__ unsigned short ss[128 * 128];  // masked scores bf16 (swz &15)
  __shared__ unsigned short sS[80 * 64];    // state rows e=0..63, z at 64, zeros 65..79
  int t = threadIdx.x, w = t >> 6, lane = t & 63, fr = lane & 15, fq = lane >> 4;
  int bh = blockIdx.x >> 5, c = blockIdx.x & 31;
  size_t qkbase = ((size_t)bh * 4096 + (size_t)c * 128) * 64;
  size_t sbase = ((size_t)bh * 32 + c) * 4096;

  u16x8 vreg[4];  // v chunk staged to regs early (T14-style)
#pragma unroll
  for (int i = 0; i < 4; ++i)
    vreg[i] = *(const u16x8*)(vb + qkbase + (size_t)(t * 4 + i) * 8);

#pragma unroll
  for (int i = 0; i < 4; ++i) {
    int p = t * 4 + i, r = p >> 3, c8 = p & 7;
    int sw = (r * 8 + (c8 ^ (r & 7))) * 8;
    *(u16x8*)&sq[sw] = *(const u16x8*)(qb + qkbase + (size_t)p * 8);
    *(u16x8*)&skv[sw] = *(const u16x8*)(kb + qkbase + (size_t)p * 8);
  }
#pragma unroll
  for (int i = 0; i < 2; ++i) {
    int p = t * 2 + i, e = p >> 3, c8 = p & 7;
    *(u16x8*)&sS[(e * 8 + (c8 ^ (e & 7))) * 8] = *(const u16x8*)(Spref + sbase + (size_t)p * 8);
  }
  if (t < 64) sS[64 * 64 + t] = f2bf(zpref[((size_t)bh * 32 + c) * 64 + t]);
  {
    unsigned int* zz = (unsigned int*)&sS[65 * 64];
    for (int i = t; i < 480; i += 256) zz[i] = 0u;
  }
  __syncthreads();

  int rowbase = w * 32;
  bf16x8 aq[2][2];
#pragma unroll
  for (int mi = 0; mi < 2; ++mi)
#pragma unroll
    for (int kt = 0; kt < 2; ++kt) {
      int r = rowbase + mi * 16 + fr;
      int c8 = (kt * 4 + fq) ^ (r & 7);
      aq[mi][kt] = *(const bf16x8*)&sq[(r * 8 + c8) * 8];
    }

  f32x4 accs[2][8];
  f32x4 z4 = {0.f, 0.f, 0.f, 0.f};
#pragma unroll
  for (int mi = 0; mi < 2; ++mi)
#pragma unroll
    for (int ni = 0; ni < 8; ++ni) accs[mi][ni] = z4;

#pragma unroll
  for (int ni = 0; ni < 8; ++ni)
#pragma unroll
    for (int kt = 0; kt < 2; ++kt) {
      int r = ni * 16 + fr;
      int c8 = (kt * 4 + fq) ^ (r & 7);
      bf16x8 bk = *(const bf16x8*)&skv[(r * 8 + c8) * 8];
      accs[0][ni] = __builtin_amdgcn_mfma_f32_16x16x32_bf16(aq[0][kt], bk, accs[0][ni], 0, 0, 0);
      accs[1][ni] = __builtin_amdgcn_mfma_f32_16x16x32_bf16(aq[1][kt], bk, accs[1][ni], 0, 0, 0);
    }

  float rs[2][4];
#pragma unroll
  for (int mi = 0; mi < 2; ++mi)
#pragma unroll
    for (int j = 0; j < 4; ++j) {
      int srow = rowbase + mi * 16 + fq * 4 + j;
      float sum = 0.f;
#pragma unroll
      for (int ni = 0; ni < 8; ++ni) {
        int scol = ni * 16 + fr;
        float v = accs[mi][ni][j];
        v = (scol <= srow) ? v : 0.f;
        accs[mi][ni][j] = v;
        sum += v;
      }
#pragma unroll
      for (int msk = 1; msk < 16; msk <<= 1) sum += __shfl_xor(sum, msk, 64);
      rs[mi][j] = sum;
    }
  __syncthreads();  // all waves done reading k from skv

  // write v^T into skv (row e, col s; swizzle &15), masked scores into ss
#pragma unroll
  for (int i = 0; i < 4; ++i) {
    int p = t * 4 + i, s = p >> 3, e0g = (p & 7) * 8;
#pragma unroll
    for (int j = 0; j < 8; ++j) {
      int e = e0g + j;
      skv[(e * 16 + ((s >> 3) ^ (e & 15))) * 8 + (s & 7)] = vreg[i][j];
    }
  }
#pragma unroll
  for (int mi = 0; mi < 2; ++mi)
#pragma unroll
    for (int ni = 0; ni < 8; ++ni)
#pragma unroll
      for (int j = 0; j < 4; ++j) {
        int srow = rowbase + mi * 16 + fq * 4 + j;
        int scol = ni * 16 + fr;
        ss[(srow * 16 + ((scol >> 3) ^ (srow & 15))) * 8 + (scol & 7)] = f2bf(accs[mi][ni][j]);
      }
  __syncthreads();

  f32x4 acco[2][4];
  f32x4 accd[2];
#pragma unroll
  for (int mi = 0; mi < 2; ++mi) {
    accd[mi] = z4;
#pragma unroll
    for (int ni = 0; ni < 4; ++ni) acco[mi][ni] = z4;
  }
  // inter-chunk: q @ S (+ den column from z row)
#pragma unroll
  for (int kt = 0; kt < 2; ++kt) {
#pragma unroll
    for (int ni = 0; ni < 4; ++ni) {
      int r = ni * 16 + fr;
      int c8 = (kt * 4 + fq) ^ (r & 7);
      bf16x8 bS = *(const bf16x8*)&sS[(r * 8 + c8) * 8];
      acco[0][ni] = __builtin_amdgcn_mfma_f32_16x16x32_bf16(aq[0][kt], bS, acco[0][ni], 0, 0, 0);
      acco[1][ni] = __builtin_amdgcn_mfma_f32_16x16x32_bf16(aq[1][kt], bS, acco[1][ni], 0, 0, 0);
    }
    {
      int r = 64 + fr;
      int c8 = (kt * 4 + fq) ^ (r & 7);
      bf16x8 bz = *(const bf16x8*)&sS[(r * 8 + c8) * 8];
      accd[0] = __builtin_amdgcn_mfma_f32_16x16x32_bf16(aq[0][kt], bz, accd[0], 0, 0, 0);
      accd[1] = __builtin_amdgcn_mfma_f32_16x16x32_bf16(aq[1][kt], bz, accd[1], 0, 0, 0);
    }
  }
  // intra-chunk: masked_scores @ v
#pragma unroll
  for (int kt = 0; kt < 4; ++kt) {
    bf16x8 am[2];
#pragma unroll
    for (int mi = 0; mi < 2; ++mi) {
      int r = rowbase + mi * 16 + fr;
      int c8 = (kt * 4 + fq) ^ (r & 15);
      am[mi] = *(const bf16x8*)&ss[(r * 16 + c8) * 8];
    }
#pragma unroll
    for (int ni = 0; ni < 4; ++ni) {
      int r = ni * 16 + fr;
      int c8 = (kt * 4 + fq) ^ (r & 15);
      bf16x8 bv = *(const bf16x8*)&skv[(r * 16 + c8) * 8];
      acco[0][ni] = __builtin_amdgcn_mfma_f32_16x16x32_bf16(am[0], bv, acco[0][ni], 0, 0, 0);
      acco[1][ni] = __builtin_amdgcn_mfma_f32_16x16x32_bf16(am[1], bv, acco[1][ni], 0, 0, 0);
    }
  }

  int b = bh >> 4, h = bh & 15;
#pragma unroll
  for (int mi = 0; mi < 2; ++mi)
#pragma unroll
    for (int j = 0; j < 4; ++j) {
      float den = __shfl(accd[mi][j], (lane & 48), 64) + rs[mi][j];
      float rden = 1.f / den;
      int m = rowbase + mi * 16 + fq * 4 + j;
      size_t rowoff = ((size_t)b * 4096 + (size_t)c * 128 + m) * 1024 + h * 64;
#pragma unroll
      for (int ni = 0; ni < 4; ++ni) {
        int e = ni * 16 + fr;
        float o = acco[mi][ni][j] * rden + 1e-12f;
        attn[rowoff + e] = f2bf(o);
      }
    }
}

// ---------------- host launch ------------------------------------------------
extern "C" void kernel_launch(void* const* d_in, const int* in_sizes, int n_in,
                              void* d_out, int out_size, void* d_ws, size_t ws_size,
                              hipStream_t stream) {
  (void)in_sizes; (void)n_in; (void)out_size; (void)ws_size;
  const float* x = (const float*)d_in[0];
  const float* Wq = (const float*)d_in[1];
  const float* Wk = (const float*)d_in[2];
  const float* Wv = (const float*)d_in[3];
  const float* Wo = (const float*)d_in[4];
  char* ws = (char*)d_ws;
  unsigned short* xbf  = (unsigned short*)(ws + 0);          // 33554432 B
  unsigned short* wqkv = (unsigned short*)(ws + 33554432);   // 6291456 B
  unsigned short* wo   = (unsigned short*)(ws + 39845888);   // 2097152 B
  unsigned short* q    = (unsigned short*)(ws + 41943040);   // 33554432 B
  unsigned short* k    = (unsigned short*)(ws + 75497472);   // 33554432 B
  unsigned short* v    = (unsigned short*)(ws + 109051904);  // 33554432 B
  unsigned short* attn = (unsigned short*)(ws + 142606336);  // 33554432 B
  float* Sbuf          = (float*)(ws + 176160768);           // 33554432 B
  unsigned short* Spref= (unsigned short*)(ws + 209715200);  // 16777216 B
  float* zbuf          = (float*)(ws + 226492416);           // 524288 B
  float* zpref         = (float*)(ws + 227016704);           // 524288 B

  cast_bf16_kernel<<<8192, 256, 0, stream>>>(x, xbf, 2097152);
  cast_bf16_kernel<<<512, 256, 0, stream>>>(Wq, wqkv, 131072);
  cast_bf16_kernel<<<512, 256, 0, stream>>>(Wk, wqkv + 1048576, 131072);
  cast_bf16_kernel<<<512, 256, 0, stream>>>(Wv, wqkv + 2097152, 131072);
  cast_bf16_kernel<<<512, 256, 0, stream>>>(Wo, wo, 131072);

  gemm_bt<1><<<3072, 256, 0, stream>>>(xbf, wqkv, nullptr, q, k, v, 1024, 3072, 24);
  chunk_state<<<2048, 256, 0, stream>>>(k, v, Sbuf, zbuf);
  scan_state<<<64, 256, 0, stream>>>(Sbuf, zbuf, Spref, zpref);
  chunk_out<<<2048, 256, 0, stream>>>(q, k, v, Spref, zpref, attn);
  gemm_bt<0><<<1024, 256, 0, stream>>>(attn, wo, d_out, nullptr, nullptr, nullptr, 1024, 1024, 8);
}

// Round 2
// 282.953 us; speedup vs baseline: 1.1977x; 1.1977x over previous
//
#include <hip/hip_runtime.h>
#include <stdint.h>

typedef float f32x4 __attribute__((ext_vector_type(4)));
typedef __bf16 bf16x8 __attribute__((ext_vector_type(8)));
typedef unsigned short u16x8 __attribute__((ext_vector_type(8)));

#define DEV __device__ __forceinline__

DEV unsigned short f2bf(float f) {
  unsigned int u = __float_as_uint(f);
  unsigned int r = (u + 0x7FFFu + ((u >> 16) & 1u)) >> 16;
  return (unsigned short)r;
}
DEV float b2f(unsigned short h) { return __uint_as_float(((unsigned int)h) << 16); }

DEV void gload16(const void* g, void* l) {
  __builtin_amdgcn_global_load_lds((__attribute__((address_space(1))) void*)(g),
                                   (__attribute__((address_space(3))) void*)(l), 16, 0, 0);
}

#define VMCNT(n) asm volatile("s_waitcnt vmcnt(" #n ")" ::: "memory")
DEV void barrier_sync() {
  __builtin_amdgcn_sched_barrier(0);
  __builtin_amdgcn_s_barrier();
  asm volatile("" ::: "memory");
  __builtin_amdgcn_sched_barrier(0);
}

// ---------------- fp32 -> bf16 cast (vectorized) ----------------
__global__ void cast_bf16_kernel(const float* __restrict__ in,
                                 unsigned short* __restrict__ out, int n8) {
  int i = blockIdx.x * 256 + threadIdx.x;
  if (i >= n8) return;
  const float4* p = (const float4*)in + (size_t)i * 2;
  float4 a = p[0], b = p[1];
  u16x8 o;
  o[0] = f2bf(a.x); o[1] = f2bf(a.y); o[2] = f2bf(a.z); o[3] = f2bf(a.w);
  o[4] = f2bf(b.x); o[5] = f2bf(b.y); o[6] = f2bf(b.z); o[7] = f2bf(b.w);
  ((u16x8*)out)[i] = o;
}

// all 4 weight matrices (1M elems each) in one launch
__global__ void cast_w4(const float* __restrict__ Wq, const float* __restrict__ Wk,
                        const float* __restrict__ Wv, const float* __restrict__ Wo,
                        unsigned short* __restrict__ wqkv, unsigned short* __restrict__ wo) {
  int i = blockIdx.x * 256 + threadIdx.x;  // 524288 8-elem units
  int sel = i >> 17, j = i & 131071;
  const float* src = (sel == 0) ? Wq : (sel == 1) ? Wk : (sel == 2) ? Wv : Wo;
  unsigned short* dst = (sel < 3) ? (wqkv + (size_t)sel * 1048576) : wo;
  const float4* p = (const float4*)src + (size_t)j * 2;
  float4 a = p[0], b = p[1];
  u16x8 o;
  o[0] = f2bf(a.x); o[1] = f2bf(a.y); o[2] = f2bf(a.z); o[3] = f2bf(a.w);
  o[4] = f2bf(b.x); o[5] = f2bf(b.y); o[6] = f2bf(b.z); o[7] = f2bf(b.w);
  ((u16x8*)dst)[j] = o;
}

// ---------------- 256x256 tile, BK=32, 4-buffer pipelined bf16 GEMM ----------
// out[m,n] = sum_k A[m,k]*W[n,k]; K = 1024 fixed (NT = 32 K-tiles).
// MODE 0: fp32 store; MODE 1: qkv scatter with elu+1 on Q,K.
#define SWZ(r) ((((r) & 3) ^ (((r) >> 2) & 3)))

template<int MODE>
__global__ __launch_bounds__(512, 2) void gemm256(
    const unsigned short* __restrict__ A, const unsigned short* __restrict__ Bw,
    void* __restrict__ out0, unsigned short* __restrict__ qp,
    unsigned short* __restrict__ kp, unsigned short* __restrict__ vp,
    int N, int nTn)
{
  __shared__ unsigned short sA[4][256 * 32];
  __shared__ unsigned short sB[4][256 * 32];
  const int K = 1024;
  int tid = threadIdx.x;
  int w = tid >> 6, lane = tid & 63, fr = lane & 15, fq = lane >> 4;
  int nwg = gridDim.x;
  int cpx = nwg >> 3;
  int swz = (blockIdx.x & 7) * cpx + (blockIdx.x >> 3);  // XCD swizzle (nwg%8==0)
  int bm = swz / nTn, bn = swz % nTn;
  int wm = w >> 2, wn = w & 3;
  const size_t rowA = (size_t)bm * 256, rowB = (size_t)bn * 256;

  // stage half-tiles: linear LDS dest, inverse-swizzled per-lane global source
  auto stageA = [&](int t) {
    unsigned short* dst = sA[t & 3];
    const unsigned short* src = A + rowA * K + t * 32;
#pragma unroll
    for (int i = 0; i < 2; ++i) {
      int idx = i * 512 + tid;
      int r = idx >> 2, c = idx & 3;
      int cs = c ^ SWZ(r);
      gload16(src + (size_t)r * K + cs * 8, dst + (i * 8 + w) * 512);
    }
  };
  auto stageB = [&](int t) {
    unsigned short* dst = sB[t & 3];
    const unsigned short* src = Bw + rowB * K + t * 32;
#pragma unroll
    for (int i = 0; i < 2; ++i) {
      int idx = i * 512 + tid;
      int r = idx >> 2, c = idx & 3;
      int cs = c ^ SWZ(r);
      gload16(src + (size_t)r * K + cs * 8, dst + (i * 8 + w) * 512);
    }
  };

  f32x4 acc[8][4];
  f32x4 z4 = {0.f, 0.f, 0.f, 0.f};
#pragma unroll
  for (int mi = 0; mi < 8; ++mi)
#pragma unroll
    for (int ni = 0; ni < 4; ++ni) acc[mi][ni] = z4;

  // prologue: tiles 0,1,2 in flight; wait tile 0 (8 instr = tiles 1,2 may fly)
  stageA(0); stageB(0); stageA(1); stageB(1); stageA(2); stageB(2);
  VMCNT(8);
  barrier_sync();

  for (int t = 0; t < 32; ++t) {
    int b = t & 3;
    bf16x8 af[4], bf[4];
    // ---- phase 0: frags mi0-3 x ni0-3 ----
#pragma unroll
    for (int i = 0; i < 4; ++i) {
      int r = wm * 128 + i * 16 + fr;
      int cs = fq ^ SWZ(r);
      af[i] = *(const bf16x8*)&sA[b][r * 32 + cs * 8];
    }
#pragma unroll
    for (int i = 0; i < 4; ++i) {
      int r = wn * 64 + i * 16 + fr;
      int cs = fq ^ SWZ(r);
      bf[i] = *(const bf16x8*)&sB[b][r * 32 + cs * 8];
    }
    if (t < 29) stageA(t + 3);
    __builtin_amdgcn_s_setprio(1);
#pragma unroll
    for (int mi = 0; mi < 4; ++mi)
#pragma unroll
      for (int ni = 0; ni < 4; ++ni)
        acc[mi][ni] = __builtin_amdgcn_mfma_f32_16x16x32_bf16(af[mi], bf[ni], acc[mi][ni], 0, 0, 0);
    __builtin_amdgcn_s_setprio(0);
    barrier_sync();
    // ---- phase 1: frags mi4-7 x ni0-3 (B reused) ----
#pragma unroll
    for (int i = 0; i < 4; ++i) {
      int r = wm * 128 + (4 + i) * 16 + fr;
      int cs = fq ^ SWZ(r);
      af[i] = *(const bf16x8*)&sA[b][r * 32 + cs * 8];
    }
    if (t < 29) stageB(t + 3);
    if (t < 29) { VMCNT(8); } else if (t == 29) { VMCNT(4); } else if (t == 30) { VMCNT(0); }
    __builtin_amdgcn_s_setprio(1);
#pragma unroll
    for (int mi = 0; mi < 4; ++mi)
#pragma unroll
      for (int ni = 0; ni < 4; ++ni)
        acc[4 + mi][ni] = __builtin_amdgcn_mfma_f32_16x16x32_bf16(af[mi], bf[ni], acc[4 + mi][ni], 0, 0, 0);
    __builtin_amdgcn_s_setprio(0);
    if (t < 31) barrier_sync();
  }

  if (MODE == 0) {
    float* O = (float*)out0;
#pragma unroll
    for (int mi = 0; mi < 8; ++mi)
#pragma unroll
      for (int ni = 0; ni < 4; ++ni)
#pragma unroll
        for (int j = 0; j < 4; ++j) {
          int m = bm * 256 + wm * 128 + mi * 16 + fq * 4 + j;
          int n = bn * 256 + wn * 64 + ni * 16 + fr;
          O[(size_t)m * N + n] = acc[mi][ni][j];
        }
  } else {
    int tsel = bn >> 2;  // 0:Q 1:K 2:V (256-col blocks never straddle 1024 boundaries)
    unsigned short* base = (tsel == 0) ? qp : ((tsel == 1) ? kp : vp);
#pragma unroll
    for (int mi = 0; mi < 8; ++mi)
#pragma unroll
      for (int ni = 0; ni < 4; ++ni)
#pragma unroll
        for (int j = 0; j < 4; ++j) {
          int m = bm * 256 + wm * 128 + mi * 16 + fq * 4 + j;  // b*4096 + l
          int n = bn * 256 + wn * 64 + ni * 16 + fr;
          int col1 = n & 1023;
          int h = col1 >> 6, d = col1 & 63;
          int b2 = m >> 12, l = m & 4095;
          float v = acc[mi][ni][j];
          if (tsel < 2) v = (v > 0.f) ? (v + 1.f) : __expf(v);  // elu(v)+1
          base[(((size_t)(b2 * 16 + h)) * 4096 + l) * 64 + d] = f2bf(v);
        }
  }
}

// ---------------- pass 1: per-chunk state S_c = k^T v (stored [e][d]), z_c ---
__global__ __launch_bounds__(256) void chunk_state(
    const unsigned short* __restrict__ kb, const unsigned short* __restrict__ vb,
    float* __restrict__ Sbuf, float* __restrict__ zbuf)
{
  __shared__ unsigned short sk[128 * 64];
  __shared__ unsigned short sv[128 * 64];
  int t = threadIdx.x, w = t >> 6;
  int bh = blockIdx.x >> 5, c = blockIdx.x & 31;
  size_t base = ((size_t)bh * 4096 + (size_t)c * 128) * 64;
#pragma unroll
  for (int i = 0; i < 4; ++i) {
    int p = (i * 4 + w) * 64 + (t & 63);
    gload16(kb + base + (size_t)p * 8, &sk[(i * 4 + w) * 512]);
    gload16(vb + base + (size_t)p * 8, &sv[(i * 4 + w) * 512]);
  }
  __syncthreads();
  int d = t >> 2, e0 = (t & 3) << 4;
  float acc[16];
#pragma unroll
  for (int j = 0; j < 16; ++j) acc[j] = 0.f;
#pragma unroll 4
  for (int s = 0; s < 128; ++s) {
    float kv = b2f(sk[s * 64 + d]);
    u16x8 v0 = *(const u16x8*)&sv[s * 64 + e0];
    u16x8 v1 = *(const u16x8*)&sv[s * 64 + e0 + 8];
#pragma unroll
    for (int j = 0; j < 8; ++j) {
      acc[j] += kv * b2f(v0[j]);
      acc[8 + j] += kv * b2f(v1[j]);
    }
  }
  // transposed store: Sbuf[bh][c][e][d] — per store-instr a wave covers 4 full lines
  size_t ob = ((size_t)bh * 32 + c) * 4096;
#pragma unroll
  for (int j = 0; j < 16; ++j)
    Sbuf[ob + (size_t)(e0 + j) * 64 + d] = acc[j];
  if (t < 64) {
    float z = 0.f;
#pragma unroll 8
    for (int s = 0; s < 128; ++s) z += b2f(sk[s * 64 + t]);
    zbuf[((size_t)bh * 32 + c) * 64 + t] = z;
  }
}

// ---------------- pass 2: fully parallel exclusive prefix over 32 chunks -----
__global__ __launch_bounds__(256) void scan_S(
    const float* __restrict__ Sbuf, unsigned short* __restrict__ Spref)
{
  int idx = blockIdx.x * 256 + threadIdx.x;  // 262144 sequences
  int bh = idx >> 12, i = idx & 4095;
  size_t base = (size_t)bh * 32 * 4096 + i;
  float run = 0.f;
#pragma unroll
  for (int c = 0; c < 32; ++c) {
    float v = Sbuf[base + (size_t)c * 4096];
    Spref[base + (size_t)c * 4096] = f2bf(run);
    run += v;
  }
}

__global__ __launch_bounds__(256) void scan_z(
    const float* __restrict__ zbuf, float* __restrict__ zpref)
{
  int idx = blockIdx.x * 256 + threadIdx.x;  // 4096 sequences
  size_t base = (size_t)(idx >> 6) * 32 * 64 + (idx & 63);
  float run = 0.f;
#pragma unroll
  for (int c = 0; c < 32; ++c) {
    float v = zbuf[base + c * 64];
    zpref[base + c * 64] = run;
    run += v;
  }
}

// ---------------- pass 3: per-chunk output ----------------------------------
__global__ __launch_bounds__(256, 2) void chunk_out(
    const unsigned short* __restrict__ qb, const unsigned short* __restrict__ kb,
    const unsigned short* __restrict__ vb, const unsigned short* __restrict__ Spref,
    const float* __restrict__ zpref, unsigned short* __restrict__ attn)
{
  __shared__ unsigned short sq[128 * 64];   // q, swizzled (&7)
  __shared__ unsigned short skv[128 * 64];  // k (swz &7), then v^T [64][128] (swz &15)
  __shared__ unsigned short ss[128 * 128];  // masked scores bf16 (swz &15)
  __shared__ unsigned short sS[80 * 64];    // state rows e=0..63, z at 64, zeros 65..79
  int t = threadIdx.x, w = t >> 6, lane = t & 63, fr = lane & 15, fq = lane >> 4;
  int bh = blockIdx.x >> 5, c = blockIdx.x & 31;
  size_t qkbase = ((size_t)bh * 4096 + (size_t)c * 128) * 64;
  size_t sbase = ((size_t)bh * 32 + c) * 4096;

  u16x8 vreg[4];  // v chunk staged to regs early (T14-style)
#pragma unroll
  for (int i = 0; i < 4; ++i)
    vreg[i] = *(const u16x8*)(vb + qkbase + (size_t)(t * 4 + i) * 8);

#pragma unroll
  for (int i = 0; i < 4; ++i) {
    int p = t * 4 + i, r = p >> 3, c8 = p & 7;
    int sw = (r * 8 + (c8 ^ (r & 7))) * 8;
    *(u16x8*)&sq[sw] = *(const u16x8*)(qb + qkbase + (size_t)p * 8);
    *(u16x8*)&skv[sw] = *(const u16x8*)(kb + qkbase + (size_t)p * 8);
  }
#pragma unroll
  for (int i = 0; i < 2; ++i) {
    int p = t * 2 + i, e = p >> 3, c8 = p & 7;
    *(u16x8*)&sS[(e * 8 + (c8 ^ (e & 7))) * 8] = *(const u16x8*)(Spref + sbase + (size_t)p * 8);
  }
  if (t < 64) sS[64 * 64 + t] = f2bf(zpref[((size_t)bh * 32 + c) * 64 + t]);
  {
    unsigned int* zz = (unsigned int*)&sS[65 * 64];
    for (int i = t; i < 480; i += 256) zz[i] = 0u;
  }
  __syncthreads();

  int rowbase = w * 32;
  bf16x8 aq[2][2];
#pragma unroll
  for (int mi = 0; mi < 2; ++mi)
#pragma unroll
    for (int kt = 0; kt < 2; ++kt) {
      int r = rowbase + mi * 16 + fr;
      int c8 = (kt * 4 + fq) ^ (r & 7);
      aq[mi][kt] = *(const bf16x8*)&sq[(r * 8 + c8) * 8];
    }

  f32x4 accs[2][8];
  f32x4 z4 = {0.f, 0.f, 0.f, 0.f};
#pragma unroll
  for (int mi = 0; mi < 2; ++mi)
#pragma unroll
    for (int ni = 0; ni < 8; ++ni) accs[mi][ni] = z4;

#pragma unroll
  for (int ni = 0; ni < 8; ++ni)
#pragma unroll
    for (int kt = 0; kt < 2; ++kt) {
      int r = ni * 16 + fr;
      int c8 = (kt * 4 + fq) ^ (r & 7);
      bf16x8 bk = *(const bf16x8*)&skv[(r * 8 + c8) * 8];
      accs[0][ni] = __builtin_amdgcn_mfma_f32_16x16x32_bf16(aq[0][kt], bk, accs[0][ni], 0, 0, 0);
      accs[1][ni] = __builtin_amdgcn_mfma_f32_16x16x32_bf16(aq[1][kt], bk, accs[1][ni], 0, 0, 0);
    }

  float rs[2][4];
#pragma unroll
  for (int mi = 0; mi < 2; ++mi)
#pragma unroll
    for (int j = 0; j < 4; ++j) {
      int srow = rowbase + mi * 16 + fq * 4 + j;
      float sum = 0.f;
#pragma unroll
      for (int ni = 0; ni < 8; ++ni) {
        int scol = ni * 16 + fr;
        float v = accs[mi][ni][j];
        v = (scol <= srow) ? v : 0.f;
        accs[mi][ni][j] = v;
        sum += v;
      }
#pragma unroll
      for (int msk = 1; msk < 16; msk <<= 1) sum += __shfl_xor(sum, msk, 64);
      rs[mi][j] = sum;
    }
  __syncthreads();  // all waves done reading k from skv

  // write v^T into skv (row e, col s; swizzle &15), masked scores into ss
#pragma unroll
  for (int i = 0; i < 4; ++i) {
    int p = t * 4 + i, s = p >> 3, e0g = (p & 7) * 8;
#pragma unroll
    for (int j = 0; j < 8; ++j) {
      int e = e0g + j;
      skv[(e * 16 + ((s >> 3) ^ (e & 15))) * 8 + (s & 7)] = vreg[i][j];
    }
  }
#pragma unroll
  for (int mi = 0; mi < 2; ++mi)
#pragma unroll
    for (int ni = 0; ni < 8; ++ni)
#pragma unroll
      for (int j = 0; j < 4; ++j) {
        int srow = rowbase + mi * 16 + fq * 4 + j;
        int scol = ni * 16 + fr;
        ss[(srow * 16 + ((scol >> 3) ^ (srow & 15))) * 8 + (scol & 7)] = f2bf(accs[mi][ni][j]);
      }
  __syncthreads();

  f32x4 acco[2][4];
  f32x4 accd[2];
#pragma unroll
  for (int mi = 0; mi < 2; ++mi) {
    accd[mi] = z4;
#pragma unroll
    for (int ni = 0; ni < 4; ++ni) acco[mi][ni] = z4;
  }
  // inter-chunk: q @ S (+ den column from z row)
#pragma unroll
  for (int kt = 0; kt < 2; ++kt) {
#pragma unroll
    for (int ni = 0; ni < 4; ++ni) {
      int r = ni * 16 + fr;
      int c8 = (kt * 4 + fq) ^ (r & 7);
      bf16x8 bS = *(const bf16x8*)&sS[(r * 8 + c8) * 8];
      acco[0][ni] = __builtin_amdgcn_mfma_f32_16x16x32_bf16(aq[0][kt], bS, acco[0][ni], 0, 0, 0);
      acco[1][ni] = __builtin_amdgcn_mfma_f32_16x16x32_bf16(aq[1][kt], bS, acco[1][ni], 0, 0, 0);
    }
    {
      int r = 64 + fr;
      int c8 = (kt * 4 + fq) ^ (r & 7);
      bf16x8 bz = *(const bf16x8*)&sS[(r * 8 + c8) * 8];
      accd[0] = __builtin_amdgcn_mfma_f32_16x16x32_bf16(aq[0][kt], bz, accd[0], 0, 0, 0);
      accd[1] = __builtin_amdgcn_mfma_f32_16x16x32_bf16(aq[1][kt], bz, accd[1], 0, 0, 0);
    }
  }
  // intra-chunk: masked_scores @ v
#pragma unroll
  for (int kt = 0; kt < 4; ++kt) {
    bf16x8 am[2];
#pragma unroll
    for (int mi = 0; mi < 2; ++mi) {
      int r = rowbase + mi * 16 + fr;
      int c8 = (kt * 4 + fq) ^ (r & 15);
      am[mi] = *(const bf16x8*)&ss[(r * 16 + c8) * 8];
    }
#pragma unroll
    for (int ni = 0; ni < 4; ++ni) {
      int r = ni * 16 + fr;
      int c8 = (kt * 4 + fq) ^ (r & 15);
      bf16x8 bv = *(const bf16x8*)&skv[(r * 16 + c8) * 8];
      acco[0][ni] = __builtin_amdgcn_mfma_f32_16x16x32_bf16(am[0], bv, acco[0][ni], 0, 0, 0);
      acco[1][ni] = __builtin_amdgcn_mfma_f32_16x16x32_bf16(am[1], bv, acco[1][ni], 0, 0, 0);
    }
  }

  int b = bh >> 4, h = bh & 15;
#pragma unroll
  for (int mi = 0; mi < 2; ++mi)
#pragma unroll
    for (int j = 0; j < 4; ++j) {
      float den = __shfl(accd[mi][j], (lane & 48), 64) + rs[mi][j];
      float rden = 1.f / den;
      int m = rowbase + mi * 16 + fq * 4 + j;
      size_t rowoff = ((size_t)b * 4096 + (size_t)c * 128 + m) * 1024 + h * 64;
#pragma unroll
      for (int ni = 0; ni < 4; ++ni) {
        int e = ni * 16 + fr;
        float o = acco[mi][ni][j] * rden + 1e-12f;
        attn[rowoff + e] = f2bf(o);
      }
    }
}

// ---------------- host launch ------------------------------------------------
extern "C" void kernel_launch(void* const* d_in, const int* in_sizes, int n_in,
                              void* d_out, int out_size, void* d_ws, size_t ws_size,
                              hipStream_t stream) {
  (void)in_sizes; (void)n_in; (void)out_size; (void)ws_size;
  const float* x = (const float*)d_in[0];
  const float* Wq = (const float*)d_in[1];
  const float* Wk = (const float*)d_in[2];
  const float* Wv = (const float*)d_in[3];
  const float* Wo = (const float*)d_in[4];
  char* ws = (char*)d_ws;
  unsigned short* xbf  = (unsigned short*)(ws + 0);          // 33554432 B
  unsigned short* wqkv = (unsigned short*)(ws + 33554432);   // 6291456 B
  unsigned short* wo   = (unsigned short*)(ws + 39845888);   // 2097152 B
  unsigned short* q    = (unsigned short*)(ws + 41943040);   // 33554432 B
  unsigned short* k    = (unsigned short*)(ws + 75497472);   // 33554432 B
  unsigned short* v    = (unsigned short*)(ws + 109051904);  // 33554432 B
  unsigned short* attn = (unsigned short*)(ws + 142606336);  // 33554432 B
  float* Sbuf          = (float*)(ws + 176160768);           // 33554432 B
  unsigned short* Spref= (unsigned short*)(ws + 209715200);  // 16777216 B
  float* zbuf          = (float*)(ws + 226492416);           // 524288 B
  float* zpref         = (float*)(ws + 227016704);           // 524288 B

  cast_bf16_kernel<<<8192, 256, 0, stream>>>(x, xbf, 2097152);
  cast_w4<<<2048, 256, 0, stream>>>(Wq, Wk, Wv, Wo, wqkv, wo);

  gemm256<1><<<768, 512, 0, stream>>>(xbf, wqkv, nullptr, q, k, v, 3072, 12);
  chunk_state<<<2048, 256, 0, stream>>>(k, v, Sbuf, zbuf);
  scan_S<<<1024, 256, 0, stream>>>(Sbuf, Spref);
  scan_z<<<16, 256, 0, stream>>>(zbuf, zpref);
  chunk_out<<<2048, 256, 0, stream>>>(q, k, v, Spref, zpref, attn);
  gemm256<0><<<256, 512, 0, stream>>>(attn, wo, d_out, nullptr, nullptr, nullptr, 1024, 4);
}

// Round 3
// 281.218 us; speedup vs baseline: 1.2051x; 1.0062x over previous
//
#include <hip/hip_runtime.h>
#include <stdint.h>

typedef float f32x4 __attribute__((ext_vector_type(4)));
typedef __bf16 bf16x8 __attribute__((ext_vector_type(8)));
typedef unsigned short u16x8 __attribute__((ext_vector_type(8)));

#define DEV __device__ __forceinline__

DEV unsigned short f2bf(float f) {
  unsigned int u = __float_as_uint(f);
  unsigned int r = (u + 0x7FFFu + ((u >> 16) & 1u)) >> 16;
  return (unsigned short)r;
}
DEV float b2f(unsigned short h) { return __uint_as_float(((unsigned int)h) << 16); }

DEV void gload16(const void* g, void* l) {
  __builtin_amdgcn_global_load_lds((__attribute__((address_space(1))) void*)(g),
                                   (__attribute__((address_space(3))) void*)(l), 16, 0, 0);
}

#define VMCNT(n) asm volatile("s_waitcnt vmcnt(" #n ")" ::: "memory")
#define LGK0 do { asm volatile("s_waitcnt lgkmcnt(0)" ::: "memory"); __builtin_amdgcn_sched_barrier(0); } while (0)
DEV void barrier_sync() {
  __builtin_amdgcn_sched_barrier(0);
  __builtin_amdgcn_s_barrier();
  asm volatile("" ::: "memory");
  __builtin_amdgcn_sched_barrier(0);
}

// ---------------- fp32 -> bf16 cast (vectorized) ----------------
__global__ void cast_bf16_kernel(const float* __restrict__ in,
                                 unsigned short* __restrict__ out, int n8) {
  int i = blockIdx.x * 256 + threadIdx.x;
  if (i >= n8) return;
  const float4* p = (const float4*)in + (size_t)i * 2;
  float4 a = p[0], b = p[1];
  u16x8 o;
  o[0] = f2bf(a.x); o[1] = f2bf(a.y); o[2] = f2bf(a.z); o[3] = f2bf(a.w);
  o[4] = f2bf(b.x); o[5] = f2bf(b.y); o[6] = f2bf(b.z); o[7] = f2bf(b.w);
  ((u16x8*)out)[i] = o;
}

// all 4 weight matrices (1M elems each) in one launch
__global__ void cast_w4(const float* __restrict__ Wq, const float* __restrict__ Wk,
                        const float* __restrict__ Wv, const float* __restrict__ Wo,
                        unsigned short* __restrict__ wqkv, unsigned short* __restrict__ wo) {
  int i = blockIdx.x * 256 + threadIdx.x;  // 524288 8-elem units
  int sel = i >> 17, j = i & 131071;
  const float* src = (sel == 0) ? Wq : (sel == 1) ? Wk : (sel == 2) ? Wv : Wo;
  unsigned short* dst = (sel < 3) ? (wqkv + (size_t)sel * 1048576) : wo;
  const float4* p = (const float4*)src + (size_t)j * 2;
  float4 a = p[0], b = p[1];
  u16x8 o;
  o[0] = f2bf(a.x); o[1] = f2bf(a.y); o[2] = f2bf(a.z); o[3] = f2bf(a.w);
  o[4] = f2bf(b.x); o[5] = f2bf(b.y); o[6] = f2bf(b.z); o[7] = f2bf(b.w);
  ((u16x8*)dst)[j] = o;
}

// ---------------- 256x256 tile, BK=64, 4-phase/K-tile pipelined bf16 GEMM ----
// out[m,n] = sum_k A[m,k]*W[n,k]; K = 1024 fixed (16 K-tiles of 64).
// LDS rows are 128 B; 16B-chunk swizzle: chunk_stored = chunk ^ (row&7)
// (m201-proven conflict-free geometry). Write side: linear LDS dest via
// global_load_lds + inverse-swizzled global source (both-sides rule).
// MODE 0: fp32 store; MODE 1: qkv scatter with elu+1 on Q,K.
template<int MODE>
__global__ __launch_bounds__(512, 2) void gemm8p(
    const unsigned short* __restrict__ A, const unsigned short* __restrict__ Bw,
    void* __restrict__ out0, unsigned short* __restrict__ qp,
    unsigned short* __restrict__ kp, unsigned short* __restrict__ vp,
    int N, int nTn)
{
  __shared__ unsigned short sA[2][256 * 64];
  __shared__ unsigned short sB[2][256 * 64];
  const int K = 1024;
  int tid = threadIdx.x;
  int w = tid >> 6, lane = tid & 63, fr = lane & 15, fq = lane >> 4;
  int nwg = gridDim.x, cpx = nwg >> 3;
  int swz = (blockIdx.x & 7) * cpx + (blockIdx.x >> 3);  // XCD swizzle (nwg%8==0)
  int bm = swz / nTn, bn = swz % nTn;
  int wm = w >> 2, wn = w & 3;
  const unsigned short* Abase = A + (size_t)bm * 256 * K;
  const unsigned short* Bbase = Bw + (size_t)bn * 256 * K;

  // staging constants: chunk p = i*512+tid -> row_local = p>>3, stored chunk = p&7,
  // source chunk = (p&7) ^ (row_local&7); LDS dest wave-uniform + lane*16.
  const int rl0 = tid >> 3, sc0 = (tid & 7) ^ (rl0 & 7);
  const int p1 = 512 + tid, rl1 = p1 >> 3, sc1 = (p1 & 7) ^ (rl1 & 7);
  const int dstw = w * 512;  // elements; +4096 for i=1; +8192 for h=1

  auto stageA = [&](int t, int h) {
    const unsigned short* s = Abase + (size_t)(h * 128) * K + t * 64;
    unsigned short* d = &sA[t & 1][h * 8192];
    gload16(s + (size_t)rl0 * K + sc0 * 8, d + dstw);
    gload16(s + (size_t)rl1 * K + sc1 * 8, d + 4096 + dstw);
  };
  auto stageB = [&](int t, int h) {
    const unsigned short* s = Bbase + (size_t)(h * 128) * K + t * 64;
    unsigned short* d = &sB[t & 1][h * 8192];
    gload16(s + (size_t)rl0 * K + sc0 * 8, d + dstw);
    gload16(s + (size_t)rl1 * K + sc1 * 8, d + 4096 + dstw);
  };

  f32x4 acc[8][4];
  f32x4 z4 = {0.f, 0.f, 0.f, 0.f};
#pragma unroll
  for (int mi = 0; mi < 8; ++mi)
#pragma unroll
    for (int ni = 0; ni < 4; ++ni) acc[mi][ni] = z4;

  // prologue: tile 0 fully staged (one-time drain)
  stageA(0, 0); stageA(0, 1); stageB(0, 0); stageB(0, 1);
  VMCNT(0);
  barrier_sync();

  for (int t = 0; t < 16; ++t) {
    const unsigned short* bufA = sA[t & 1];
    const unsigned short* bufB = sB[t & 1];
    bf16x8 af[4], bg[4];

    // ---- P0: quadrant (mi 0-3) x ks0; stage A halves of t+1 ----
#pragma unroll
    for (int i = 0; i < 4; ++i) {
      int r = wn * 64 + i * 16 + fr;
      int ch = fq ^ (r & 7);
      bg[i] = *(const bf16x8*)&bufB[r * 64 + ch * 8];
    }
#pragma unroll
    for (int i = 0; i < 4; ++i) {
      int r = wm * 128 + i * 16 + fr;
      int ch = fq ^ (r & 7);
      af[i] = *(const bf16x8*)&bufA[r * 64 + ch * 8];
    }
    if (t < 15) { stageA(t + 1, 0); stageA(t + 1, 1); }
    barrier_sync();
    LGK0;
    __builtin_amdgcn_s_setprio(1);
#pragma unroll
    for (int mi = 0; mi < 4; ++mi)
#pragma unroll
      for (int ni = 0; ni < 4; ++ni)
        acc[mi][ni] = __builtin_amdgcn_mfma_f32_16x16x32_bf16(af[mi], bg[ni], acc[mi][ni], 0, 0, 0);
    __builtin_amdgcn_s_setprio(0);
    barrier_sync();

    // ---- P1: quadrant (mi 4-7) x ks0; stage B halves of t+1 ----
#pragma unroll
    for (int i = 0; i < 4; ++i) {
      int r = wm * 128 + (4 + i) * 16 + fr;
      int ch = fq ^ (r & 7);
      af[i] = *(const bf16x8*)&bufA[r * 64 + ch * 8];
    }
    if (t < 15) { stageB(t + 1, 0); stageB(t + 1, 1); }
    barrier_sync();
    LGK0;
    __builtin_amdgcn_s_setprio(1);
#pragma unroll
    for (int mi = 0; mi < 4; ++mi)
#pragma unroll
      for (int ni = 0; ni < 4; ++ni)
        acc[4 + mi][ni] = __builtin_amdgcn_mfma_f32_16x16x32_bf16(af[mi], bg[ni], acc[4 + mi][ni], 0, 0, 0);
    __builtin_amdgcn_s_setprio(0);
    barrier_sync();

    // ---- P2: quadrant (mi 0-3) x ks1 ----
#pragma unroll
    for (int i = 0; i < 4; ++i) {
      int r = wn * 64 + i * 16 + fr;
      int ch = (4 + fq) ^ (r & 7);
      bg[i] = *(const bf16x8*)&bufB[r * 64 + ch * 8];
    }
#pragma unroll
    for (int i = 0; i < 4; ++i) {
      int r = wm * 128 + i * 16 + fr;
      int ch = (4 + fq) ^ (r & 7);
      af[i] = *(const bf16x8*)&bufA[r * 64 + ch * 8];
    }
    barrier_sync();
    LGK0;
    __builtin_amdgcn_s_setprio(1);
#pragma unroll
    for (int mi = 0; mi < 4; ++mi)
#pragma unroll
      for (int ni = 0; ni < 4; ++ni)
        acc[mi][ni] = __builtin_amdgcn_mfma_f32_16x16x32_bf16(af[mi], bg[ni], acc[mi][ni], 0, 0, 0);
    __builtin_amdgcn_s_setprio(0);
    barrier_sync();

    // ---- P3: quadrant (mi 4-7) x ks1; counted drain for t+1's stages ----
#pragma unroll
    for (int i = 0; i < 4; ++i) {
      int r = wm * 128 + (4 + i) * 16 + fr;
      int ch = (4 + fq) ^ (r & 7);
      af[i] = *(const bf16x8*)&bufA[r * 64 + ch * 8];
    }
    barrier_sync();
    LGK0;
    __builtin_amdgcn_s_setprio(1);
#pragma unroll
    for (int mi = 0; mi < 4; ++mi)
#pragma unroll
      for (int ni = 0; ni < 4; ++ni)
        acc[4 + mi][ni] = __builtin_amdgcn_mfma_f32_16x16x32_bf16(af[mi], bg[ni], acc[4 + mi][ni], 0, 0, 0);
    __builtin_amdgcn_s_setprio(0);
    VMCNT(0);  // t+1's stages issued 2.5-3.5 phases ago -> drain ~free
    barrier_sync();
  }

  if (MODE == 0) {
    float* O = (float*)out0;
#pragma unroll
    for (int mi = 0; mi < 8; ++mi)
#pragma unroll
      for (int ni = 0; ni < 4; ++ni)
#pragma unroll
        for (int j = 0; j < 4; ++j) {
          int m = bm * 256 + wm * 128 + mi * 16 + fq * 4 + j;
          int n = bn * 256 + wn * 64 + ni * 16 + fr;
          O[(size_t)m * N + n] = acc[mi][ni][j];
        }
  } else {
    int tsel = bn >> 2;  // 0:Q 1:K 2:V (256-col blocks never straddle 1024 boundaries)
    unsigned short* base = (tsel == 0) ? qp : ((tsel == 1) ? kp : vp);
#pragma unroll
    for (int mi = 0; mi < 8; ++mi)
#pragma unroll
      for (int ni = 0; ni < 4; ++ni)
#pragma unroll
        for (int j = 0; j < 4; ++j) {
          int m = bm * 256 + wm * 128 + mi * 16 + fq * 4 + j;  // b*4096 + l
          int n = bn * 256 + wn * 64 + ni * 16 + fr;
          int col1 = n & 1023;
          int h = col1 >> 6, d = col1 & 63;
          int b2 = m >> 12, l = m & 4095;
          float v = acc[mi][ni][j];
          if (tsel < 2) v = (v > 0.f) ? (v + 1.f) : __expf(v);  // elu(v)+1
          base[(((size_t)(b2 * 16 + h)) * 4096 + l) * 64 + d] = f2bf(v);
        }
  }
}

// ---------------- pass 1: per-chunk state S_c = k^T v (stored [e][d]), z_c ---
__global__ __launch_bounds__(256) void chunk_state(
    const unsigned short* __restrict__ kb, const unsigned short* __restrict__ vb,
    float* __restrict__ Sbuf, float* __restrict__ zbuf)
{
  __shared__ unsigned short sk[128 * 64];
  __shared__ unsigned short sv[128 * 64];
  int t = threadIdx.x, w = t >> 6;
  int bh = blockIdx.x >> 5, c = blockIdx.x & 31;
  size_t base = ((size_t)bh * 4096 + (size_t)c * 128) * 64;
#pragma unroll
  for (int i = 0; i < 4; ++i) {
    int p = (i * 4 + w) * 64 + (t & 63);
    gload16(kb + base + (size_t)p * 8, &sk[(i * 4 + w) * 512]);
    gload16(vb + base + (size_t)p * 8, &sv[(i * 4 + w) * 512]);
  }
  __syncthreads();
  int d = t >> 2, e0 = (t & 3) << 4;
  float acc[16];
#pragma unroll
  for (int j = 0; j < 16; ++j) acc[j] = 0.f;
#pragma unroll 4
  for (int s = 0; s < 128; ++s) {
    float kv = b2f(sk[s * 64 + d]);
    u16x8 v0 = *(const u16x8*)&sv[s * 64 + e0];
    u16x8 v1 = *(const u16x8*)&sv[s * 64 + e0 + 8];
#pragma unroll
    for (int j = 0; j < 8; ++j) {
      acc[j] += kv * b2f(v0[j]);
      acc[8 + j] += kv * b2f(v1[j]);
    }
  }
  // transposed store: Sbuf[bh][c][e][d]
  size_t ob = ((size_t)bh * 32 + c) * 4096;
#pragma unroll
  for (int j = 0; j < 16; ++j)
    Sbuf[ob + (size_t)(e0 + j) * 64 + d] = acc[j];
  if (t < 64) {
    float z = 0.f;
#pragma unroll 8
    for (int s = 0; s < 128; ++s) z += b2f(sk[s * 64 + t]);
    zbuf[((size_t)bh * 32 + c) * 64 + t] = z;
  }
}

// ---------------- pass 2: fully parallel exclusive prefix over 32 chunks -----
__global__ __launch_bounds__(256) void scan_S(
    const float* __restrict__ Sbuf, unsigned short* __restrict__ Spref)
{
  int idx = blockIdx.x * 256 + threadIdx.x;  // 262144 sequences
  int bh = idx >> 12, i = idx & 4095;
  size_t base = (size_t)bh * 32 * 4096 + i;
  float run = 0.f;
#pragma unroll
  for (int c = 0; c < 32; ++c) {
    float v = Sbuf[base + (size_t)c * 4096];
    Spref[base + (size_t)c * 4096] = f2bf(run);
    run += v;
  }
}

__global__ __launch_bounds__(256) void scan_z(
    const float* __restrict__ zbuf, float* __restrict__ zpref)
{
  int idx = blockIdx.x * 256 + threadIdx.x;  // 4096 sequences
  size_t base = (size_t)(idx >> 6) * 32 * 64 + (idx & 63);
  float run = 0.f;
#pragma unroll
  for (int c = 0; c < 32; ++c) {
    float v = zbuf[base + c * 64];
    zpref[base + c * 64] = run;
    run += v;
  }
}

// ---------------- pass 3: per-chunk output ----------------------------------
__global__ __launch_bounds__(256, 2) void chunk_out(
    const unsigned short* __restrict__ qb, const unsigned short* __restrict__ kb,
    const unsigned short* __restrict__ vb, const unsigned short* __restrict__ Spref,
    const float* __restrict__ zpref, unsigned short* __restrict__ attn)
{
  __shared__ unsigned short sq[128 * 64];   // q, swizzled (&7)
  __shared__ unsigned short skv[128 * 64];  // k (swz &7), then v^T [64][128] (swz &15)
  __shared__ unsigned short ss[128 * 128];  // masked scores bf16 (swz &15)
  __shared__ unsigned short sS[80 * 64];    // state rows e=0..63, z at 64, zeros 65..79
  int t = threadIdx.x, w = t >> 6, lane = t & 63, fr = lane & 15, fq = lane >> 4;
  int bh = blockIdx.x >> 5, c = blockIdx.x & 31;
  size_t qkbase = ((size_t)bh * 4096 + (size_t)c * 128) * 64;
  size_t sbase = ((size_t)bh * 32 + c) * 4096;

  u16x8 vreg[4];  // v chunk staged to regs early (T14-style)
#pragma unroll
  for (int i = 0; i < 4; ++i)
    vreg[i] = *(const u16x8*)(vb + qkbase + (size_t)(t * 4 + i) * 8);

#pragma unroll
  for (int i = 0; i < 4; ++i) {
    int p = t * 4 + i, r = p >> 3, c8 = p & 7;
    int sw = (r * 8 + (c8 ^ (r & 7))) * 8;
    *(u16x8*)&sq[sw] = *(const u16x8*)(qb + qkbase + (size_t)p * 8);
    *(u16x8*)&skv[sw] = *(const u16x8*)(kb + qkbase + (size_t)p * 8);
  }
#pragma unroll
  for (int i = 0; i < 2; ++i) {
    int p = t * 2 + i, e = p >> 3, c8 = p & 7;
    *(u16x8*)&sS[(e * 8 + (c8 ^ (e & 7))) * 8] = *(const u16x8*)(Spref + sbase + (size_t)p * 8);
  }
  if (t < 64) sS[64 * 64 + t] = f2bf(zpref[((size_t)bh * 32 + c) * 64 + t]);
  {
    unsigned int* zz = (unsigned int*)&sS[65 * 64];
    for (int i = t; i < 480; i += 256) zz[i] = 0u;
  }
  __syncthreads();

  int rowbase = w * 32;
  bf16x8 aq[2][2];
#pragma unroll
  for (int mi = 0; mi < 2; ++mi)
#pragma unroll
    for (int kt = 0; kt < 2; ++kt) {
      int r = rowbase + mi * 16 + fr;
      int c8 = (kt * 4 + fq) ^ (r & 7);
      aq[mi][kt] = *(const bf16x8*)&sq[(r * 8 + c8) * 8];
    }

  f32x4 accs[2][8];
  f32x4 z4 = {0.f, 0.f, 0.f, 0.f};
#pragma unroll
  for (int mi = 0; mi < 2; ++mi)
#pragma unroll
    for (int ni = 0; ni < 8; ++ni) accs[mi][ni] = z4;

#pragma unroll
  for (int ni = 0; ni < 8; ++ni)
#pragma unroll
    for (int kt = 0; kt < 2; ++kt) {
      int r = ni * 16 + fr;
      int c8 = (kt * 4 + fq) ^ (r & 7);
      bf16x8 bk = *(const bf16x8*)&skv[(r * 8 + c8) * 8];
      accs[0][ni] = __builtin_amdgcn_mfma_f32_16x16x32_bf16(aq[0][kt], bk, accs[0][ni], 0, 0, 0);
      accs[1][ni] = __builtin_amdgcn_mfma_f32_16x16x32_bf16(aq[1][kt], bk, accs[1][ni], 0, 0, 0);
    }

  float rs[2][4];
#pragma unroll
  for (int mi = 0; mi < 2; ++mi)
#pragma unroll
    for (int j = 0; j < 4; ++j) {
      int srow = rowbase + mi * 16 + fq * 4 + j;
      float sum = 0.f;
#pragma unroll
      for (int ni = 0; ni < 8; ++ni) {
        int scol = ni * 16 + fr;
        float v = accs[mi][ni][j];
        v = (scol <= srow) ? v : 0.f;
        accs[mi][ni][j] = v;
        sum += v;
      }
#pragma unroll
      for (int msk = 1; msk < 16; msk <<= 1) sum += __shfl_xor(sum, msk, 64);
      rs[mi][j] = sum;
    }
  __syncthreads();  // all waves done reading k from skv

  // write v^T into skv (row e, col s; swizzle &15), masked scores into ss
#pragma unroll
  for (int i = 0; i < 4; ++i) {
    int p = t * 4 + i, s = p >> 3, e0g = (p & 7) * 8;
#pragma unroll
    for (int j = 0; j < 8; ++j) {
      int e = e0g + j;
      skv[(e * 16 + ((s >> 3) ^ (e & 15))) * 8 + (s & 7)] = vreg[i][j];
    }
  }
#pragma unroll
  for (int mi = 0; mi < 2; ++mi)
#pragma unroll
    for (int ni = 0; ni < 8; ++ni)
#pragma unroll
      for (int j = 0; j < 4; ++j) {
        int srow = rowbase + mi * 16 + fq * 4 + j;
        int scol = ni * 16 + fr;
        ss[(srow * 16 + ((scol >> 3) ^ (srow & 15))) * 8 + (scol & 7)] = f2bf(accs[mi][ni][j]);
      }
  __syncthreads();

  f32x4 acco[2][4];
  f32x4 accd[2];
#pragma unroll
  for (int mi = 0; mi < 2; ++mi) {
    accd[mi] = z4;
#pragma unroll
    for (int ni = 0; ni < 4; ++ni) acco[mi][ni] = z4;
  }
  // inter-chunk: q @ S (+ den column from z row)
#pragma unroll
  for (int kt = 0; kt < 2; ++kt) {
#pragma unroll
    for (int ni = 0; ni < 4; ++ni) {
      int r = ni * 16 + fr;
      int c8 = (kt * 4 + fq) ^ (r & 7);
      bf16x8 bS = *(const bf16x8*)&sS[(r * 8 + c8) * 8];
      acco[0][ni] = __builtin_amdgcn_mfma_f32_16x16x32_bf16(aq[0][kt], bS, acco[0][ni], 0, 0, 0);
      acco[1][ni] = __builtin_amdgcn_mfma_f32_16x16x32_bf16(aq[1][kt], bS, acco[1][ni], 0, 0, 0);
    }
    {
      int r = 64 + fr;
      int c8 = (kt * 4 + fq) ^ (r & 7);
      bf16x8 bz = *(const bf16x8*)&sS[(r * 8 + c8) * 8];
      accd[0] = __builtin_amdgcn_mfma_f32_16x16x32_bf16(aq[0][kt], bz, accd[0], 0, 0, 0);
      accd[1] = __builtin_amdgcn_mfma_f32_16x16x32_bf16(aq[1][kt], bz, accd[1], 0, 0, 0);
    }
  }
  // intra-chunk: masked_scores @ v
#pragma unroll
  for (int kt = 0; kt < 4; ++kt) {
    bf16x8 am[2];
#pragma unroll
    for (int mi = 0; mi < 2; ++mi) {
      int r = rowbase + mi * 16 + fr;
      int c8 = (kt * 4 + fq) ^ (r & 15);
      am[mi] = *(const bf16x8*)&ss[(r * 16 + c8) * 8];
    }
#pragma unroll
    for (int ni = 0; ni < 4; ++ni) {
      int r = ni * 16 + fr;
      int c8 = (kt * 4 + fq) ^ (r & 15);
      bf16x8 bv = *(const bf16x8*)&skv[(r * 16 + c8) * 8];
      acco[0][ni] = __builtin_amdgcn_mfma_f32_16x16x32_bf16(am[0], bv, acco[0][ni], 0, 0, 0);
      acco[1][ni] = __builtin_amdgcn_mfma_f32_16x16x32_bf16(am[1], bv, acco[1][ni], 0, 0, 0);
    }
  }

  int b = bh >> 4, h = bh & 15;
#pragma unroll
  for (int mi = 0; mi < 2; ++mi)
#pragma unroll
    for (int j = 0; j < 4; ++j) {
      float den = __shfl(accd[mi][j], (lane & 48), 64) + rs[mi][j];
      float rden = 1.f / den;
      int m = rowbase + mi * 16 + fq * 4 + j;
      size_t rowoff = ((size_t)b * 4096 + (size_t)c * 128 + m) * 1024 + h * 64;
#pragma unroll
      for (int ni = 0; ni < 4; ++ni) {
        int e = ni * 16 + fr;
        float o = acco[mi][ni][j] * rden + 1e-12f;
        attn[rowoff + e] = f2bf(o);
      }
    }
}

// ---------------- host launch ------------------------------------------------
extern "C" void kernel_launch(void* const* d_in, const int* in_sizes, int n_in,
                              void* d_out, int out_size, void* d_ws, size_t ws_size,
                              hipStream_t stream) {
  (void)in_sizes; (void)n_in; (void)out_size; (void)ws_size;
  const float* x = (const float*)d_in[0];
  const float* Wq = (const float*)d_in[1];
  const float* Wk = (const float*)d_in[2];
  const float* Wv = (const float*)d_in[3];
  const float* Wo = (const float*)d_in[4];
  char* ws = (char*)d_ws;
  unsigned short* xbf  = (unsigned short*)(ws + 0);          // 33554432 B
  unsigned short* wqkv = (unsigned short*)(ws + 33554432);   // 6291456 B
  unsigned short* wo   = (unsigned short*)(ws + 39845888);   // 2097152 B
  unsigned short* q    = (unsigned short*)(ws + 41943040);   // 33554432 B
  unsigned short* k    = (unsigned short*)(ws + 75497472);   // 33554432 B
  unsigned short* v    = (unsigned short*)(ws + 109051904);  // 33554432 B
  unsigned short* attn = (unsigned short*)(ws + 142606336);  // 33554432 B
  float* Sbuf          = (float*)(ws + 176160768);           // 33554432 B
  unsigned short* Spref= (unsigned short*)(ws + 209715200);  // 16777216 B
  float* zbuf          = (float*)(ws + 226492416);           // 524288 B
  float* zpref         = (float*)(ws + 227016704);           // 524288 B

  cast_bf16_kernel<<<8192, 256, 0, stream>>>(x, xbf, 2097152);
  cast_w4<<<2048, 256, 0, stream>>>(Wq, Wk, Wv, Wo, wqkv, wo);

  gemm8p<1><<<768, 512, 0, stream>>>(xbf, wqkv, nullptr, q, k, v, 3072, 12);
  chunk_state<<<2048, 256, 0, stream>>>(k, v, Sbuf, zbuf);
  scan_S<<<1024, 256, 0, stream>>>(Sbuf, Spref);
  scan_z<<<16, 256, 0, stream>>>(zbuf, zpref);
  chunk_out<<<2048, 256, 0, stream>>>(q, k, v, Spref, zpref, attn);
  gemm8p<0><<<256, 512, 0, stream>>>(attn, wo, d_out, nullptr, nullptr, nullptr, 1024, 4);
}

// Round 4
// 234.760 us; speedup vs baseline: 1.4436x; 1.1979x over previous
//
#include <hip/hip_runtime.h>
#include <stdint.h>

typedef float f32x4 __attribute__((ext_vector_type(4)));
typedef __bf16 bf16x8 __attribute__((ext_vector_type(8)));
typedef unsigned short u16x8 __attribute__((ext_vector_type(8)));

#define DEV __device__ __forceinline__

DEV unsigned short f2bf(float f) {
  unsigned int u = __float_as_uint(f);
  unsigned int r = (u + 0x7FFFu + ((u >> 16) & 1u)) >> 16;
  return (unsigned short)r;
}
DEV float b2f(unsigned short h) { return __uint_as_float(((unsigned int)h) << 16); }

DEV void gload16(const void* g, void* l) {
  __builtin_amdgcn_global_load_lds((__attribute__((address_space(1))) void*)(g),
                                   (__attribute__((address_space(3))) void*)(l), 16, 0, 0);
}

// ---------------- fp32 -> bf16 cast (vectorized) ----------------
__global__ void cast_bf16_kernel(const float* __restrict__ in,
                                 unsigned short* __restrict__ out, int n8) {
  int i = blockIdx.x * 256 + threadIdx.x;
  if (i >= n8) return;
  const float4* p = (const float4*)in + (size_t)i * 2;
  float4 a = p[0], b = p[1];
  u16x8 o;
  o[0] = f2bf(a.x); o[1] = f2bf(a.y); o[2] = f2bf(a.z); o[3] = f2bf(a.w);
  o[4] = f2bf(b.x); o[5] = f2bf(b.y); o[6] = f2bf(b.z); o[7] = f2bf(b.w);
  ((u16x8*)out)[i] = o;
}

// all 4 weight matrices (1M elems each) in one launch
__global__ void cast_w4(const float* __restrict__ Wq, const float* __restrict__ Wk,
                        const float* __restrict__ Wv, const float* __restrict__ Wo,
                        unsigned short* __restrict__ wqkv, unsigned short* __restrict__ wo) {
  int i = blockIdx.x * 256 + threadIdx.x;  // 524288 8-elem units
  int sel = i >> 17, j = i & 131071;
  const float* src = (sel == 0) ? Wq : (sel == 1) ? Wk : (sel == 2) ? Wv : Wo;
  unsigned short* dst = (sel < 3) ? (wqkv + (size_t)sel * 1048576) : wo;
  const float4* p = (const float4*)src + (size_t)j * 2;
  float4 a = p[0], b = p[1];
  u16x8 o;
  o[0] = f2bf(a.x); o[1] = f2bf(a.y); o[2] = f2bf(a.z); o[3] = f2bf(a.w);
  o[4] = f2bf(b.x); o[5] = f2bf(b.y); o[6] = f2bf(b.z); o[7] = f2bf(b.w);
  ((u16x8*)dst)[j] = o;
}

// ---------------- bf16 GEMM, B^T layout (out[m,n] = sum_k A[m,k]*W[n,k]) ----
// Round-1 structure (128x128 tile, BK=64, multi-block/CU implicit overlap;
// measured 104.7us / 45% MfmaUtil / 0 conflicts) + bijective XCD swizzle.
// MODE 0: plain fp32 store; MODE 1: qkv scatter with elu+1 on Q,K.
template<int MODE>
__global__ __launch_bounds__(256, 2) void gemm_bt(
    const unsigned short* __restrict__ A, const unsigned short* __restrict__ Bw,
    void* __restrict__ out0, unsigned short* __restrict__ qp,
    unsigned short* __restrict__ kp, unsigned short* __restrict__ vp,
    int K, int N, int nTn)
{
  __shared__ unsigned short sA[128 * 64];
  __shared__ unsigned short sB[128 * 64];
  int t = threadIdx.x, w = t >> 6, lane = t & 63, fr = lane & 15, fq = lane >> 4;
  int nwg = gridDim.x, cpx = nwg >> 3;
  int bid = (blockIdx.x & 7) * cpx + (blockIdx.x >> 3);  // XCD swizzle (nwg%8==0)
  int bm = bid / nTn, bn = bid % nTn;
  int wm = w >> 1, wn = w & 1;

  f32x4 acc[4][4];
  f32x4 z4 = {0.f, 0.f, 0.f, 0.f};
#pragma unroll
  for (int mi = 0; mi < 4; ++mi)
#pragma unroll
    for (int ni = 0; ni < 4; ++ni) acc[mi][ni] = z4;

  for (int k0 = 0; k0 < K; k0 += 64) {
#pragma unroll
    for (int i = 0; i < 4; ++i) {
      int p = (i * 4 + w) * 64 + lane;
      int r = p >> 3;
      int c8 = (p & 7) ^ (r & 7);  // inverse-swizzled source column-chunk
      gload16(A + (size_t)(bm * 128 + r) * K + k0 + c8 * 8, &sA[(i * 4 + w) * 512]);
      gload16(Bw + (size_t)(bn * 128 + r) * K + k0 + c8 * 8, &sB[(i * 4 + w) * 512]);
    }
    __syncthreads();
#pragma unroll
    for (int ks = 0; ks < 2; ++ks) {
      bf16x8 af[4], bg[4];
#pragma unroll
      for (int mi = 0; mi < 4; ++mi) {
        int r = wm * 64 + mi * 16 + fr;
        int c8 = (ks * 4 + fq) ^ (r & 7);
        af[mi] = *(const bf16x8*)&sA[(r * 8 + c8) * 8];
      }
#pragma unroll
      for (int ni = 0; ni < 4; ++ni) {
        int r = wn * 64 + ni * 16 + fr;
        int c8 = (ks * 4 + fq) ^ (r & 7);
        bg[ni] = *(const bf16x8*)&sB[(r * 8 + c8) * 8];
      }
#pragma unroll
      for (int mi = 0; mi < 4; ++mi)
#pragma unroll
        for (int ni = 0; ni < 4; ++ni)
          acc[mi][ni] = __builtin_amdgcn_mfma_f32_16x16x32_bf16(af[mi], bg[ni], acc[mi][ni], 0, 0, 0);
    }
    __syncthreads();
  }

  if (MODE == 0) {
    float* O = (float*)out0;
#pragma unroll
    for (int mi = 0; mi < 4; ++mi)
#pragma unroll
      for (int ni = 0; ni < 4; ++ni)
#pragma unroll
        for (int j = 0; j < 4; ++j) {
          int m = bm * 128 + wm * 64 + mi * 16 + fq * 4 + j;
          int n = bn * 128 + wn * 64 + ni * 16 + fr;
          O[(size_t)m * N + n] = acc[mi][ni][j];
        }
  } else {
    int tsel = (bn * 128) >> 10;  // 0:Q 1:K 2:V (whole block in one tensor)
    unsigned short* base = (tsel == 0) ? qp : ((tsel == 1) ? kp : vp);
#pragma unroll
    for (int mi = 0; mi < 4; ++mi)
#pragma unroll
      for (int ni = 0; ni < 4; ++ni)
#pragma unroll
        for (int j = 0; j < 4; ++j) {
          int m = bm * 128 + wm * 64 + mi * 16 + fq * 4 + j;  // b*4096 + l
          int n = bn * 128 + wn * 64 + ni * 16 + fr;
          int col1 = n & 1023;
          int h = col1 >> 6, d = col1 & 63;
          int b = m >> 12, l = m & 4095;
          float v = acc[mi][ni][j];
          if (tsel < 2) v = (v > 0.f) ? (v + 1.f) : __expf(v);  // elu(v)+1
          base[(((size_t)(b * 16 + h)) * 4096 + l) * 64 + d] = f2bf(v);
        }
  }
}

// ---------------- pass 1: per-chunk state via MFMA ---------------------------
// S_c[e][d] = sum_s v[s][e]*k[s][d]  (stored Sbuf[bh][c][e][d]); z_c[d] = sum_s k[s][d]
// k,v staged transposed into LDS [d][s] (row stride 136 elems = 16B-aligned).
__global__ __launch_bounds__(256) void chunk_state(
    const unsigned short* __restrict__ kb, const unsigned short* __restrict__ vb,
    float* __restrict__ Sbuf, float* __restrict__ zbuf)
{
  __shared__ unsigned short kT[64 * 136];
  __shared__ unsigned short vT[64 * 136];
  int t = threadIdx.x, w = t >> 6, lane = t & 63, fr = lane & 15, fq = lane >> 4;
  int bh = blockIdx.x >> 5, c = blockIdx.x & 31;
  size_t base = ((size_t)bh * 4096 + (size_t)c * 128) * 64;

  int s = t >> 1, d0 = (t & 1) * 32;
  const unsigned short* kpp = kb + base + (size_t)s * 64 + d0;
  const unsigned short* vpp = vb + base + (size_t)s * 64 + d0;
#pragma unroll
  for (int i = 0; i < 4; ++i) {
    u16x8 kr = *(const u16x8*)(kpp + i * 8);
    u16x8 vr = *(const u16x8*)(vpp + i * 8);
#pragma unroll
    for (int j = 0; j < 8; ++j) {
      int d = d0 + i * 8 + j;
      kT[d * 136 + s] = kr[j];
      vT[d * 136 + s] = vr[j];
    }
  }
  __syncthreads();

  // wave w owns e-tile w (rows w*16..w*16+15); 4 d-tiles; K=128 in 4 steps
  f32x4 acc[4];
  f32x4 z4 = {0.f, 0.f, 0.f, 0.f};
#pragma unroll
  for (int n = 0; n < 4; ++n) acc[n] = z4;
#pragma unroll
  for (int ks = 0; ks < 4; ++ks) {
    bf16x8 av = *(const bf16x8*)&vT[(w * 16 + fr) * 136 + ks * 32 + fq * 8];
#pragma unroll
    for (int n = 0; n < 4; ++n) {
      bf16x8 bk = *(const bf16x8*)&kT[(n * 16 + fr) * 136 + ks * 32 + fq * 8];
      acc[n] = __builtin_amdgcn_mfma_f32_16x16x32_bf16(av, bk, acc[n], 0, 0, 0);
    }
  }
  size_t ob = ((size_t)bh * 32 + c) * 4096;
#pragma unroll
  for (int n = 0; n < 4; ++n)
#pragma unroll
    for (int j = 0; j < 4; ++j) {
      int e = w * 16 + fq * 4 + j, d = n * 16 + fr;
      Sbuf[ob + (size_t)e * 64 + d] = acc[n][j];
    }
  if (t < 64) {
    float z = 0.f;
#pragma unroll
    for (int i = 0; i < 16; ++i) {
      u16x8 kr = *(const u16x8*)&kT[t * 136 + i * 8];
#pragma unroll
      for (int j = 0; j < 8; ++j) z += b2f(kr[j]);
    }
    zbuf[((size_t)bh * 32 + c) * 64 + t] = z;
  }
}

// ---------------- pass 2: fully parallel exclusive prefix over 32 chunks -----
__global__ __launch_bounds__(256) void scan_S(
    const float* __restrict__ Sbuf, unsigned short* __restrict__ Spref)
{
  int idx = blockIdx.x * 256 + threadIdx.x;  // 262144 sequences
  int bh = idx >> 12, i = idx & 4095;
  size_t base = (size_t)bh * 32 * 4096 + i;
  float run = 0.f;
#pragma unroll
  for (int c = 0; c < 32; ++c) {
    float v = Sbuf[base + (size_t)c * 4096];
    Spref[base + (size_t)c * 4096] = f2bf(run);
    run += v;
  }
}

__global__ __launch_bounds__(256) void scan_z(
    const float* __restrict__ zbuf, float* __restrict__ zpref)
{
  int idx = blockIdx.x * 256 + threadIdx.x;  // 4096 sequences
  size_t base = (size_t)(idx >> 6) * 32 * 64 + (idx & 63);
  float run = 0.f;
#pragma unroll
  for (int c = 0; c < 32; ++c) {
    float v = zbuf[base + c * 64];
    zpref[base + c * 64] = run;
    run += v;
  }
}

// ---------------- pass 3: per-chunk output ----------------------------------
__global__ __launch_bounds__(256, 2) void chunk_out(
    const unsigned short* __restrict__ qb, const unsigned short* __restrict__ kb,
    const unsigned short* __restrict__ vb, const unsigned short* __restrict__ Spref,
    const float* __restrict__ zpref, unsigned short* __restrict__ attn)
{
  __shared__ unsigned short sq[128 * 64];   // q, swizzled (&7)
  __shared__ unsigned short skv[128 * 64];  // k (swz &7), then v^T [64][128] (swz &15)
  __shared__ unsigned short ss[128 * 128];  // masked scores bf16 (swz &15)
  __shared__ unsigned short sS[80 * 64];    // state rows e=0..63, z at 64, zeros 65..79
  int t = threadIdx.x, w = t >> 6, lane = t & 63, fr = lane & 15, fq = lane >> 4;
  int bh = blockIdx.x >> 5, c = blockIdx.x & 31;
  size_t qkbase = ((size_t)bh * 4096 + (size_t)c * 128) * 64;
  size_t sbase = ((size_t)bh * 32 + c) * 4096;

  u16x8 vreg[4];  // v chunk staged to regs early (T14-style)
#pragma unroll
  for (int i = 0; i < 4; ++i)
    vreg[i] = *(const u16x8*)(vb + qkbase + (size_t)(t * 4 + i) * 8);

#pragma unroll
  for (int i = 0; i < 4; ++i) {
    int p = t * 4 + i, r = p >> 3, c8 = p & 7;
    int sw = (r * 8 + (c8 ^ (r & 7))) * 8;
    *(u16x8*)&sq[sw] = *(const u16x8*)(qb + qkbase + (size_t)p * 8);
    *(u16x8*)&skv[sw] = *(const u16x8*)(kb + qkbase + (size_t)p * 8);
  }
#pragma unroll
  for (int i = 0; i < 2; ++i) {
    int p = t * 2 + i, e = p >> 3, c8 = p & 7;
    *(u16x8*)&sS[(e * 8 + (c8 ^ (e & 7))) * 8] = *(const u16x8*)(Spref + sbase + (size_t)p * 8);
  }
  if (t < 64) sS[64 * 64 + t] = f2bf(zpref[((size_t)bh * 32 + c) * 64 + t]);
  {
    unsigned int* zz = (unsigned int*)&sS[65 * 64];
    for (int i = t; i < 480; i += 256) zz[i] = 0u;
  }
  __syncthreads();

  int rowbase = w * 32;
  bf16x8 aq[2][2];
#pragma unroll
  for (int mi = 0; mi < 2; ++mi)
#pragma unroll
    for (int kt = 0; kt < 2; ++kt) {
      int r = rowbase + mi * 16 + fr;
      int c8 = (kt * 4 + fq) ^ (r & 7);
      aq[mi][kt] = *(const bf16x8*)&sq[(r * 8 + c8) * 8];
    }

  f32x4 accs[2][8];
  f32x4 z4 = {0.f, 0.f, 0.f, 0.f};
#pragma unroll
  for (int mi = 0; mi < 2; ++mi)
#pragma unroll
    for (int ni = 0; ni < 8; ++ni) accs[mi][ni] = z4;

#pragma unroll
  for (int ni = 0; ni < 8; ++ni)
#pragma unroll
    for (int kt = 0; kt < 2; ++kt) {
      int r = ni * 16 + fr;
      int c8 = (kt * 4 + fq) ^ (r & 7);
      bf16x8 bk = *(const bf16x8*)&skv[(r * 8 + c8) * 8];
      accs[0][ni] = __builtin_amdgcn_mfma_f32_16x16x32_bf16(aq[0][kt], bk, accs[0][ni], 0, 0, 0);
      accs[1][ni] = __builtin_amdgcn_mfma_f32_16x16x32_bf16(aq[1][kt], bk, accs[1][ni], 0, 0, 0);
    }

  float rs[2][4];
#pragma unroll
  for (int mi = 0; mi < 2; ++mi)
#pragma unroll
    for (int j = 0; j < 4; ++j) {
      int srow = rowbase + mi * 16 + fq * 4 + j;
      float sum = 0.f;
#pragma unroll
      for (int ni = 0; ni < 8; ++ni) {
        int scol = ni * 16 + fr;
        float v = accs[mi][ni][j];
        v = (scol <= srow) ? v : 0.f;
        accs[mi][ni][j] = v;
        sum += v;
      }
#pragma unroll
      for (int msk = 1; msk < 16; msk <<= 1) sum += __shfl_xor(sum, msk, 64);
      rs[mi][j] = sum;
    }
  __syncthreads();  // all waves done reading k from skv

  // write v^T into skv (row e, col s; swizzle &15), masked scores into ss
#pragma unroll
  for (int i = 0; i < 4; ++i) {
    int p = t * 4 + i, s = p >> 3, e0g = (p & 7) * 8;
#pragma unroll
    for (int j = 0; j < 8; ++j) {
      int e = e0g + j;
      skv[(e * 16 + ((s >> 3) ^ (e & 15))) * 8 + (s & 7)] = vreg[i][j];
    }
  }
#pragma unroll
  for (int mi = 0; mi < 2; ++mi)
#pragma unroll
    for (int ni = 0; ni < 8; ++ni)
#pragma unroll
      for (int j = 0; j < 4; ++j) {
        int srow = rowbase + mi * 16 + fq * 4 + j;
        int scol = ni * 16 + fr;
        ss[(srow * 16 + ((scol >> 3) ^ (srow & 15))) * 8 + (scol & 7)] = f2bf(accs[mi][ni][j]);
      }
  __syncthreads();

  f32x4 acco[2][4];
  f32x4 accd[2];
#pragma unroll
  for (int mi = 0; mi < 2; ++mi) {
    accd[mi] = z4;
#pragma unroll
    for (int ni = 0; ni < 4; ++ni) acco[mi][ni] = z4;
  }
  // inter-chunk: q @ S (+ den column from z row)
#pragma unroll
  for (int kt = 0; kt < 2; ++kt) {
#pragma unroll
    for (int ni = 0; ni < 4; ++ni) {
      int r = ni * 16 + fr;
      int c8 = (kt * 4 + fq) ^ (r & 7);
      bf16x8 bS = *(const bf16x8*)&sS[(r * 8 + c8) * 8];
      acco[0][ni] = __builtin_amdgcn_mfma_f32_16x16x32_bf16(aq[0][kt], bS, acco[0][ni], 0, 0, 0);
      acco[1][ni] = __builtin_amdgcn_mfma_f32_16x16x32_bf16(aq[1][kt], bS, acco[1][ni], 0, 0, 0);
    }
    {
      int r = 64 + fr;
      int c8 = (kt * 4 + fq) ^ (r & 7);
      bf16x8 bz = *(const bf16x8*)&sS[(r * 8 + c8) * 8];
      accd[0] = __builtin_amdgcn_mfma_f32_16x16x32_bf16(aq[0][kt], bz, accd[0], 0, 0, 0);
      accd[1] = __builtin_amdgcn_mfma_f32_16x16x32_bf16(aq[1][kt], bz, accd[1], 0, 0, 0);
    }
  }
  // intra-chunk: masked_scores @ v
#pragma unroll
  for (int kt = 0; kt < 4; ++kt) {
    bf16x8 am[2];
#pragma unroll
    for (int mi = 0; mi < 2; ++mi) {
      int r = rowbase + mi * 16 + fr;
      int c8 = (kt * 4 + fq) ^ (r & 15);
      am[mi] = *(const bf16x8*)&ss[(r * 16 + c8) * 8];
    }
#pragma unroll
    for (int ni = 0; ni < 4; ++ni) {
      int r = ni * 16 + fr;
      int c8 = (kt * 4 + fq) ^ (r & 15);
      bf16x8 bv = *(const bf16x8*)&skv[(r * 16 + c8) * 8];
      acco[0][ni] = __builtin_amdgcn_mfma_f32_16x16x32_bf16(am[0], bv, acco[0][ni], 0, 0, 0);
      acco[1][ni] = __builtin_amdgcn_mfma_f32_16x16x32_bf16(am[1], bv, acco[1][ni], 0, 0, 0);
    }
  }

  int b = bh >> 4, h = bh & 15;
#pragma unroll
  for (int mi = 0; mi < 2; ++mi)
#pragma unroll
    for (int j = 0; j < 4; ++j) {
      float den = __shfl(accd[mi][j], (lane & 48), 64) + rs[mi][j];
      float rden = 1.f / den;
      int m = rowbase + mi * 16 + fq * 4 + j;
      size_t rowoff = ((size_t)b * 4096 + (size_t)c * 128 + m) * 1024 + h * 64;
#pragma unroll
      for (int ni = 0; ni < 4; ++ni) {
        int e = ni * 16 + fr;
        float o = acco[mi][ni][j] * rden + 1e-12f;
        attn[rowoff + e] = f2bf(o);
      }
    }
}

// ---------------- host launch ------------------------------------------------
extern "C" void kernel_launch(void* const* d_in, const int* in_sizes, int n_in,
                              void* d_out, int out_size, void* d_ws, size_t ws_size,
                              hipStream_t stream) {
  (void)in_sizes; (void)n_in; (void)out_size; (void)ws_size;
  const float* x = (const float*)d_in[0];
  const float* Wq = (const float*)d_in[1];
  const float* Wk = (const float*)d_in[2];
  const float* Wv = (const float*)d_in[3];
  const float* Wo = (const float*)d_in[4];
  char* ws = (char*)d_ws;
  unsigned short* xbf  = (unsigned short*)(ws + 0);          // 33554432 B
  unsigned short* wqkv = (unsigned short*)(ws + 33554432);   // 6291456 B
  unsigned short* wo   = (unsigned short*)(ws + 39845888);   // 2097152 B
  unsigned short* q    = (unsigned short*)(ws + 41943040);   // 33554432 B
  unsigned short* k    = (unsigned short*)(ws + 75497472);   // 33554432 B
  unsigned short* v    = (unsigned short*)(ws + 109051904);  // 33554432 B
  unsigned short* attn = (unsigned short*)(ws + 142606336);  // 33554432 B
  float* Sbuf          = (float*)(ws + 176160768);           // 33554432 B
  unsigned short* Spref= (unsigned short*)(ws + 209715200);  // 16777216 B
  float* zbuf          = (float*)(ws + 226492416);           // 524288 B
  float* zpref         = (float*)(ws + 227016704);           // 524288 B

  cast_bf16_kernel<<<8192, 256, 0, stream>>>(x, xbf, 2097152);
  cast_w4<<<2048, 256, 0, stream>>>(Wq, Wk, Wv, Wo, wqkv, wo);

  gemm_bt<1><<<3072, 256, 0, stream>>>(xbf, wqkv, nullptr, q, k, v, 1024, 3072, 24);
  chunk_state<<<2048, 256, 0, stream>>>(k, v, Sbuf, zbuf);
  scan_S<<<1024, 256, 0, stream>>>(Sbuf, Spref);
  scan_z<<<16, 256, 0, stream>>>(zbuf, zpref);
  chunk_out<<<2048, 256, 0, stream>>>(q, k, v, Spref, zpref, attn);
  gemm_bt<0><<<1024, 256, 0, stream>>>(attn, wo, d_out, nullptr, nullptr, nullptr, 1024, 1024, 8);
}